// Round 5
// baseline (475.760 us; speedup 1.0000x reference)
//
#include <hip/hip_runtime.h>
#include <hip/hip_bf16.h>
#include <type_traits>

#define NV 23
#define NTOT 16384
#define FLAT (NV * 256)    // 5888
#define FLAT4 (FLAT / 4)   // 1472
#define NB 32              // n per block (multiple of 4)
#define WAVES 16
#define CH (FLAT4 / WAVES) // 92 f32x4 per wave
#define NS 2               // ceil(92/64) reg slots

typedef short s16x8 __attribute__((ext_vector_type(8)));
typedef float f32x4 __attribute__((ext_vector_type(4)));
typedef unsigned u32x4 __attribute__((ext_vector_type(4)));

template <int V> using Ic = std::integral_constant<int, V>;

// x/23 for 0 <= x < 61681
__device__ __forceinline__ int divNV(int x) { return (int)(((unsigned)x * 45591u) >> 20); }
// f32 -> bf16 bits, RNE
__device__ __forceinline__ unsigned f2bf(float f) {
  unsigned u = __float_as_uint(f);
  u += 0x7fffu + ((u >> 16) & 1u);
  return u >> 16;
}

// ws layout (bytes): Wt@0 (131072) | tab@131072 (23552) | sum@154624 | ssq@178176
//                    | An2@201728 | Bn2@225280  -> 248832 total
__global__ void k_prep(const float* __restrict__ W, const float* __restrict__ mask,
                       short* __restrict__ Wt, unsigned* __restrict__ tab,
                       float* __restrict__ sums) {
  int idx = blockIdx.x * 256 + threadIdx.x;  // grid 256 -> 65536
  int d = idx >> 8, c = idx & 255;
  Wt[idx] = (short)f2bf(W[c * 256 + d]);     // W^T in bf16: Wt[d][c]
  if (idx < FLAT) {
    // p = idx = c*23 + v ; w = (v - c) mod 23 ; swizzled LDS byte offset
    int cc = divNV(idx);
    int v = idx - NV * cc;
    int cm = cc - NV * divNV(cc);
    int w = v - cm; w += (w >> 31) & NV;
    unsigned off = (unsigned)((w << 9) + ((cc << 1) ^ ((w & 7) << 4)));
    tab[idx] = (f2bf(tanhf(mask[(w << 8) + cc]) + 1.0f) << 16) | off;
  }
  if (idx < 2 * FLAT) sums[idx] = 0.0f;      // zero sum+ssq
}

__global__ void k_finalize(const float* __restrict__ sum, const float* __restrict__ ssq,
                           const float* __restrict__ bnw, const float* __restrict__ bnb,
                           float* __restrict__ An2, float* __restrict__ Bn2) {
  int idx = blockIdx.x * 256 + threadIdx.x;  // (w,d) feature in y-space
  if (idx >= FLAT) return;
  int w = idx >> 8, d = idx & 255;
  float mean = sum[idx] * (1.0f / NTOT);
  float var  = ssq[idx] * (1.0f / NTOT) - mean * mean;
  float inv  = rsqrtf(var + 1e-5f);
  int i = w + d; i -= NV * divNV(i);         // out-shift row i = (w+d) % 23
  float a = inv * bnw[i * 256 + d];
  An2[d * NV + i] = a;                       // j-indexed (flat out order)
  Bn2[d * NV + i] = bnb[i * 256 + d] - mean * a;
}

// WRITE=0: stats pass.  WRITE=1: recompute + normalize + residual + relu.
// 16 waves x 64; wave wv owns d-strip [wv*16, wv*16+16) and slab chunk
// [wv*CH, (wv+1)*CH) f32x4 == exactly that d-strip's flat out region.
// 4-deep register prefetch of x0 slabs, 4-phase unrolled pipeline.
// NOTE launch_bounds: 2nd arg behaves like CUDA's min-blocks-per-CU here
// (R2/R4 evidence: arg=4 forced a 64-VGPR cap -> catastrophic spills).
// arg=1 + 1024-thread block forces compiler <=128 VGPR, no spills, 1 block/CU.
template <int WRITE>
__global__ __launch_bounds__(1024, 1) void k_gemm(
    const float* __restrict__ x0, const short* __restrict__ Wt,
    const unsigned* __restrict__ tab, float* __restrict__ sum, float* __restrict__ ssq,
    const float* __restrict__ An2, const float* __restrict__ Bn2,
    float* __restrict__ out) {
  extern __shared__ char smem[];     // Xb0@0, Xb1@16384, O@32768 (WRITE only)
  float* O = (float*)(smem + 32768);

  const int tid = threadIdx.x;
  const int lane = tid & 63;
  const int wv = tid >> 6;
  const int l15 = lane & 15;
  const int lg = lane >> 4;
  const int d0 = wv * 16;
  const int ch0 = wv * CH;

  // B fragments, register-resident (32 VGPR): B[k=c][n=d] = Wt[d][c]
  s16x8 bfr[8];
#pragma unroll
  for (int kt = 0; kt < 8; ++kt)
    bfr[kt] = *(const s16x8*)(Wt + (d0 + l15) * 256 + kt * 32 + lg * 8);

  // formation table, register-resident (n-invariant)
  u32x4 tbr[NS];
#pragma unroll
  for (int s = 0; s < NS; ++s)
    if (s * 64 + lane < CH) tbr[s] = *(const u32x4*)(tab + 4 * (ch0 + s * 64 + lane));

  // BN affine tables, register-resident (n-invariant), WRITE only
  f32x4 anr[NS], bnr[NS];
  if (WRITE) {
#pragma unroll
    for (int s = 0; s < NS; ++s)
      if (s * 64 + lane < CH) {
        anr[s] = *(const f32x4*)(An2 + 4 * (ch0 + s * 64 + lane));
        bnr[s] = *(const f32x4*)(Bn2 + 4 * (ch0 + s * 64 + lane));
      }
  }

  // zero pad rows 23..31 of both X' buffers (never written again)
  for (int i = tid; i < 2304; i += 1024) {
    int b = i >= 1152;
    *(int*)(smem + b * 16384 + 11776 + (i - b * 1152) * 4) = 0;
  }

  f32x4 acc[2];
  float s1[2][4], s2[2][4];
  if (!WRITE) {
#pragma unroll
    for (int mt = 0; mt < 2; ++mt)
#pragma unroll
      for (int r = 0; r < 4; ++r) { s1[mt][r] = 0.f; s2[mt][r] = 0.f; }
  }

  const int nbase = blockIdx.x * NB;
  // pass 2 runs its window in reverse: pass 1 left the tail L3-resident
  auto nmap = [&](int T) { return nbase + (WRITE ? (NB - 1 - T) : T); };

  f32x4 xr[4][NS];  // 4-deep register prefetch of x0 slabs

  auto loadx = [&](auto SL, int T) {
    const f32x4* xg = (const f32x4*)(x0 + (size_t)nmap(T) * FLAT);
#pragma unroll
    for (int s = 0; s < NS; ++s)
      if (s * 64 + lane < CH) {
        if (WRITE)
          xr[SL.value][s] = __builtin_nontemporal_load(xg + ch0 + s * 64 + lane);
        else
          xr[SL.value][s] = xg[ch0 + s * 64 + lane];
      }
  };
  auto form = [&](auto BUF, auto SL) {  // X' formation into Xb[BUF] from xr[SL]
    char* xb = smem + BUF.value * 16384;
#pragma unroll
    for (int s = 0; s < NS; ++s)
      if (s * 64 + lane < CH) {
        u32x4 tb = tbr[s];
        f32x4 xv = xr[SL.value][s];
#pragma unroll
        for (int e = 0; e < 4; ++e) {
          unsigned tt = tb[e];
          *(short*)(xb + (tt & 0xffffu)) =
              (short)f2bf(xv[e] * __uint_as_float(tt & 0xffff0000u));
        }
      }
  };
  auto mstep = [&](auto BUF) {  // y = X' * W on Xb[BUF]
    const char* xb = smem + BUF.value * 16384;
#pragma unroll
    for (int kt = 0; kt < 8; ++kt) {
      s16x8 af[2];
#pragma unroll
      for (int mt = 0; mt < 2; ++mt) {
        int row = mt * 16 + l15;
        af[mt] = *(const s16x8*)(xb + (row << 9) +
                                 (((kt * 32 + lg * 8) << 1) ^ ((row & 7) << 4)));
      }
#pragma unroll
      for (int mt = 0; mt < 2; ++mt)
        acc[mt] = __builtin_amdgcn_mfma_f32_16x16x32_bf16(af[mt], bfr[kt], acc[mt], 0, 0, 0);
    }
  };
  auto sstep = [&]() {
#pragma unroll
    for (int mt = 0; mt < 2; ++mt)
#pragma unroll
      for (int r = 0; r < 4; ++r) {
        float y = acc[mt][r];
        s1[mt][r] += y;
        s2[mt][r] += y * y;
      }
  };
  auto wstep = [&](auto SL, int T) {
    // scatter y -> O at out-shifted j = d*23 + (w+d)%23 (wave-local region!)
#pragma unroll
    for (int mt = 0; mt < 2; ++mt)
#pragma unroll
      for (int r = 0; r < 4; ++r) {
        int w = mt * 16 + lg * 4 + r;  // C/D: row = (lane>>4)*4 + reg
        if (w < NV) {
          int d = d0 + l15;            // col = lane & 15
          int sj = w + d; sj -= NV * divNV(sj);
          O[d * NV + sj] = acc[mt][r];
        }
      }
    // same-wave read-back (no barrier): normalize + residual(from regs) + relu
    float* og = out + (size_t)nmap(T) * FLAT;
#pragma unroll
    for (int s = 0; s < NS; ++s)
      if (s * 64 + lane < CH) {
        int i = ch0 + s * 64 + lane;
        f32x4 y = *(const f32x4*)(O + 4 * i);
        f32x4 o;
#pragma unroll
        for (int e = 0; e < 4; ++e)
          o[e] = fmaxf(fmaf(y[e], anr[s][e], bnr[s][e]) + xr[SL.value][s][e], 0.0f);
        __builtin_nontemporal_store(o, (f32x4*)og + i);
      }
  };
  auto bar = []() {  // LDS-drain barrier: does NOT drain vmcnt (prefetch survives)
    asm volatile("s_waitcnt lgkmcnt(0)" ::: "memory");
    __builtin_amdgcn_s_barrier();
    asm volatile("" ::: "memory");
  };

  // prologue: fill all 4 prefetch slots, form slab 0
  loadx(Ic<0>{}, 0);
  loadx(Ic<1>{}, 1);
  loadx(Ic<2>{}, 2);
  loadx(Ic<3>{}, 3);
  form(Ic<0>{}, Ic<0>{});
  bar();

  // phase P of iteration t: consume slab t+P from Xb[P&1], form slab t+P+1
  // into Xb[(P+1)&1] from slot (P+1)&3, epilogue slab t+P (resid slot P),
  // prefetch slab t+P+4 into slot P.
#define PHASE(P)                                                        \
  do {                                                                  \
    _Pragma("unroll") for (int mt = 0; mt < 2; ++mt)                    \
        acc[mt] = (f32x4){0.f, 0.f, 0.f, 0.f};                          \
    mstep(Ic<(P) & 1>{});                                               \
    if (t + (P) + 1 < NB) form(Ic<((P) + 1) & 1>{}, Ic<((P) + 1) & 3>{}); \
    if (!WRITE) sstep(); else wstep(Ic<(P)>{}, t + (P));                \
    if (t + (P) + 4 < NB) loadx(Ic<(P)>{}, t + (P) + 4);                \
    bar();                                                              \
  } while (0)

  for (int t = 0; t < NB; t += 4) {
    PHASE(0);
    PHASE(1);
    PHASE(2);
    PHASE(3);
  }
#undef PHASE

  if (!WRITE) {
#pragma unroll
    for (int mt = 0; mt < 2; ++mt)
#pragma unroll
      for (int r = 0; r < 4; ++r) {
        int w = mt * 16 + lg * 4 + r;
        if (w < NV) {
          int d = d0 + l15;
          atomicAdd(sum + (w << 8) + d, s1[mt][r]);
          atomicAdd(ssq + (w << 8) + d, s2[mt][r]);
        }
      }
  }
}

extern "C" void kernel_launch(void* const* d_in, const int* in_sizes, int n_in,
                              void* d_out, int out_size, void* d_ws, size_t ws_size,
                              hipStream_t stream) {
  const float* x0   = (const float*)d_in[0];
  const float* W    = (const float*)d_in[1];
  // d_in[2] = bias: cancels inside BN -> unused
  const float* mask = (const float*)d_in[3];
  const float* bnw  = (const float*)d_in[4];
  const float* bnb  = (const float*)d_in[5];
  // d_in[6], d_in[7] = shift tables: folded into addressing
  float* out = (float*)d_out;

  char* ws = (char*)d_ws;
  short* Wt     = (short*)ws;
  unsigned* tab = (unsigned*)(ws + 131072);
  float* sum    = (float*)(ws + 154624);
  float* ssq    = (float*)(ws + 178176);
  float* An2    = (float*)(ws + 201728);
  float* Bn2    = (float*)(ws + 225280);

  k_prep<<<256, 256, 0, stream>>>(W, mask, Wt, tab, sum);
  k_gemm<0><<<512, 1024, 32768, stream>>>(x0, Wt, tab, sum, ssq, nullptr, nullptr, nullptr);
  k_finalize<<<23, 256, 0, stream>>>(sum, ssq, bnw, bnb, An2, Bn2);
  k_gemm<1><<<512, 1024, 56320, stream>>>(x0, Wt, tab, sum, ssq, An2, Bn2, out);
}

// Round 6
// 475.541 us; speedup vs baseline: 1.0005x; 1.0005x over previous
//
#include <hip/hip_runtime.h>
#include <hip/hip_bf16.h>
#include <type_traits>

#define NV 23
#define NTOT 16384
#define FLAT (NV * 256)    // 5888
#define FLAT4 (FLAT / 4)   // 1472
#define NB 32              // n per block (multiple of 4)
#define WAVES 16
#define CH (FLAT4 / WAVES) // 92 f32x4 per wave
#define NS 2               // ceil(92/64) reg slots

typedef short s16x8 __attribute__((ext_vector_type(8)));
typedef float f32x4 __attribute__((ext_vector_type(4)));
typedef unsigned u32x4 __attribute__((ext_vector_type(4)));

template <int V> using Ic = std::integral_constant<int, V>;

// x/23 for 0 <= x < 61681
__device__ __forceinline__ int divNV(int x) { return (int)(((unsigned)x * 45591u) >> 20); }
// f32 -> bf16 bits, RNE
__device__ __forceinline__ unsigned f2bf(float f) {
  unsigned u = __float_as_uint(f);
  u += 0x7fffu + ((u >> 16) & 1u);
  return u >> 16;
}

// ws layout (bytes): Wt@0 (131072) | tab@131072 (23552) | sum@154624 | ssq@178176
//                    | An2@201728 | Bn2@225280  -> 248832 total
__global__ void k_prep(const float* __restrict__ W, const float* __restrict__ mask,
                       short* __restrict__ Wt, unsigned* __restrict__ tab,
                       float* __restrict__ sums) {
  int idx = blockIdx.x * 256 + threadIdx.x;  // grid 256 -> 65536
  int d = idx >> 8, c = idx & 255;
  Wt[idx] = (short)f2bf(W[c * 256 + d]);     // W^T in bf16: Wt[d][c]
  if (idx < FLAT) {
    // p = idx = c*23 + v ; w = (v - c) mod 23 ; swizzled LDS byte offset
    int cc = divNV(idx);
    int v = idx - NV * cc;
    int cm = cc - NV * divNV(cc);
    int w = v - cm; w += (w >> 31) & NV;
    unsigned off = (unsigned)((w << 9) + ((cc << 1) ^ ((w & 7) << 4)));
    tab[idx] = (f2bf(tanhf(mask[(w << 8) + cc]) + 1.0f) << 16) | off;
  }
  if (idx < 2 * FLAT) sums[idx] = 0.0f;      // zero sum+ssq
}

__global__ void k_finalize(const float* __restrict__ sum, const float* __restrict__ ssq,
                           const float* __restrict__ bnw, const float* __restrict__ bnb,
                           float* __restrict__ An2, float* __restrict__ Bn2) {
  int idx = blockIdx.x * 256 + threadIdx.x;  // (w,d) feature in y-space
  if (idx >= FLAT) return;
  int w = idx >> 8, d = idx & 255;
  float mean = sum[idx] * (1.0f / NTOT);
  float var  = ssq[idx] * (1.0f / NTOT) - mean * mean;
  float inv  = rsqrtf(var + 1e-5f);
  int i = w + d; i -= NV * divNV(i);         // out-shift row i = (w+d) % 23
  float a = inv * bnw[i * 256 + d];
  An2[d * NV + i] = a;                       // j-indexed (flat out order)
  Bn2[d * NV + i] = bnb[i * 256 + d] - mean * a;
}

// WRITE=0: stats pass.  WRITE=1: recompute + normalize + residual + relu.
// 16 waves x 64; wave wv owns d-strip [wv*16, wv*16+16) and slab chunk
// [wv*CH, (wv+1)*CH) f32x4 == exactly that d-strip's flat out region.
// 4-deep register prefetch of x0 slabs, 4-phase unrolled pipeline.
//
// REGISTER BUDGET (R5 post-mortem): __launch_bounds__ only caps VGPRs; the
// allocator's own heuristic targeted 8 waves/EU = 64 VGPR and spilled ~50
// regs to (L2-resident) scratch -> every phase ate ~200cy scratch latency
// (VGPR_Count=64, VALUBusy 8.7%, 712 GB/s). amdgpu_waves_per_eu(4,4) pins
// the target at 4 waves/EU = 128 VGPR budget; demand ~111 -> zero spill.
template <int WRITE>
__global__ __attribute__((amdgpu_flat_work_group_size(1024, 1024),
                          amdgpu_waves_per_eu(4, 4))) void k_gemm(
    const float* __restrict__ x0, const short* __restrict__ Wt,
    const unsigned* __restrict__ tab, float* __restrict__ sum, float* __restrict__ ssq,
    const float* __restrict__ An2, const float* __restrict__ Bn2,
    float* __restrict__ out) {
  extern __shared__ char smem[];     // Xb0@0, Xb1@16384, O@32768 (WRITE only)
  float* O = (float*)(smem + 32768);

  const int tid = threadIdx.x;
  const int lane = tid & 63;
  const int wv = tid >> 6;
  const int l15 = lane & 15;
  const int lg = lane >> 4;
  const int d0 = wv * 16;
  const int ch0 = wv * CH;

  // B fragments, register-resident (32 VGPR): B[k=c][n=d] = Wt[d][c]
  s16x8 bfr[8];
#pragma unroll
  for (int kt = 0; kt < 8; ++kt)
    bfr[kt] = *(const s16x8*)(Wt + (d0 + l15) * 256 + kt * 32 + lg * 8);

  // formation table, register-resident (n-invariant)
  u32x4 tbr[NS];
#pragma unroll
  for (int s = 0; s < NS; ++s)
    if (s * 64 + lane < CH) tbr[s] = *(const u32x4*)(tab + 4 * (ch0 + s * 64 + lane));

  // BN affine tables, register-resident (n-invariant), WRITE only
  f32x4 anr[NS], bnr[NS];
  if (WRITE) {
#pragma unroll
    for (int s = 0; s < NS; ++s)
      if (s * 64 + lane < CH) {
        anr[s] = *(const f32x4*)(An2 + 4 * (ch0 + s * 64 + lane));
        bnr[s] = *(const f32x4*)(Bn2 + 4 * (ch0 + s * 64 + lane));
      }
  }

  // zero pad rows 23..31 of both X' buffers (never written again)
  for (int i = tid; i < 2304; i += 1024) {
    int b = i >= 1152;
    *(int*)(smem + b * 16384 + 11776 + (i - b * 1152) * 4) = 0;
  }

  f32x4 acc[2];
  float s1[2][4], s2[2][4];
  if (!WRITE) {
#pragma unroll
    for (int mt = 0; mt < 2; ++mt)
#pragma unroll
      for (int r = 0; r < 4; ++r) { s1[mt][r] = 0.f; s2[mt][r] = 0.f; }
  }

  const int nbase = blockIdx.x * NB;
  // pass 2 runs its window in reverse: pass 1 left the tail L3-resident
  auto nmap = [&](int T) { return nbase + (WRITE ? (NB - 1 - T) : T); };

  f32x4 xr[4][NS];  // 4-deep register prefetch of x0 slabs

  auto loadx = [&](auto SL, int T) {
    const f32x4* xg = (const f32x4*)(x0 + (size_t)nmap(T) * FLAT);
#pragma unroll
    for (int s = 0; s < NS; ++s)
      if (s * 64 + lane < CH) {
        if (WRITE)
          xr[SL.value][s] = __builtin_nontemporal_load(xg + ch0 + s * 64 + lane);
        else
          xr[SL.value][s] = xg[ch0 + s * 64 + lane];
      }
  };
  auto form = [&](auto BUF, auto SL) {  // X' formation into Xb[BUF] from xr[SL]
    char* xb = smem + BUF.value * 16384;
#pragma unroll
    for (int s = 0; s < NS; ++s)
      if (s * 64 + lane < CH) {
        u32x4 tb = tbr[s];
        f32x4 xv = xr[SL.value][s];
#pragma unroll
        for (int e = 0; e < 4; ++e) {
          unsigned tt = tb[e];
          *(short*)(xb + (tt & 0xffffu)) =
              (short)f2bf(xv[e] * __uint_as_float(tt & 0xffff0000u));
        }
      }
  };
  auto mstep = [&](auto BUF) {  // y = X' * W on Xb[BUF]
    const char* xb = smem + BUF.value * 16384;
#pragma unroll
    for (int kt = 0; kt < 8; ++kt) {
      s16x8 af[2];
#pragma unroll
      for (int mt = 0; mt < 2; ++mt) {
        int row = mt * 16 + l15;
        af[mt] = *(const s16x8*)(xb + (row << 9) +
                                 (((kt * 32 + lg * 8) << 1) ^ ((row & 7) << 4)));
      }
#pragma unroll
      for (int mt = 0; mt < 2; ++mt)
        acc[mt] = __builtin_amdgcn_mfma_f32_16x16x32_bf16(af[mt], bfr[kt], acc[mt], 0, 0, 0);
    }
  };
  auto sstep = [&]() {
#pragma unroll
    for (int mt = 0; mt < 2; ++mt)
#pragma unroll
      for (int r = 0; r < 4; ++r) {
        float y = acc[mt][r];
        s1[mt][r] += y;
        s2[mt][r] += y * y;
      }
  };
  auto wstep = [&](auto SL, int T) {
    // scatter y -> O at out-shifted j = d*23 + (w+d)%23 (wave-local region!)
#pragma unroll
    for (int mt = 0; mt < 2; ++mt)
#pragma unroll
      for (int r = 0; r < 4; ++r) {
        int w = mt * 16 + lg * 4 + r;  // C/D: row = (lane>>4)*4 + reg
        if (w < NV) {
          int d = d0 + l15;            // col = lane & 15
          int sj = w + d; sj -= NV * divNV(sj);
          O[d * NV + sj] = acc[mt][r];
        }
      }
    // same-wave read-back (no barrier): normalize + residual(from regs) + relu
    float* og = out + (size_t)nmap(T) * FLAT;
#pragma unroll
    for (int s = 0; s < NS; ++s)
      if (s * 64 + lane < CH) {
        int i = ch0 + s * 64 + lane;
        f32x4 y = *(const f32x4*)(O + 4 * i);
        f32x4 o;
#pragma unroll
        for (int e = 0; e < 4; ++e)
          o[e] = fmaxf(fmaf(y[e], anr[s][e], bnr[s][e]) + xr[SL.value][s][e], 0.0f);
        __builtin_nontemporal_store(o, (f32x4*)og + i);
      }
  };
  auto bar = []() {  // LDS-drain barrier: does NOT drain vmcnt (prefetch survives)
    asm volatile("s_waitcnt lgkmcnt(0)" ::: "memory");
    __builtin_amdgcn_s_barrier();
    asm volatile("" ::: "memory");
  };

  // prologue: fill all 4 prefetch slots, form slab 0
  loadx(Ic<0>{}, 0);
  loadx(Ic<1>{}, 1);
  loadx(Ic<2>{}, 2);
  loadx(Ic<3>{}, 3);
  form(Ic<0>{}, Ic<0>{});
  bar();

  // phase P of iteration t: consume slab t+P from Xb[P&1], form slab t+P+1
  // into Xb[(P+1)&1] from slot (P+1)&3, epilogue slab t+P (resid slot P),
  // prefetch slab t+P+4 into slot P.
#define PHASE(P)                                                        \
  do {                                                                  \
    _Pragma("unroll") for (int mt = 0; mt < 2; ++mt)                    \
        acc[mt] = (f32x4){0.f, 0.f, 0.f, 0.f};                          \
    mstep(Ic<(P) & 1>{});                                               \
    if (t + (P) + 1 < NB) form(Ic<((P) + 1) & 1>{}, Ic<((P) + 1) & 3>{}); \
    if (!WRITE) sstep(); else wstep(Ic<(P)>{}, t + (P));                \
    if (t + (P) + 4 < NB) loadx(Ic<(P)>{}, t + (P) + 4);                \
    bar();                                                              \
  } while (0)

  for (int t = 0; t < NB; t += 4) {
    PHASE(0);
    PHASE(1);
    PHASE(2);
    PHASE(3);
  }
#undef PHASE

  if (!WRITE) {
#pragma unroll
    for (int mt = 0; mt < 2; ++mt)
#pragma unroll
      for (int r = 0; r < 4; ++r) {
        int w = mt * 16 + lg * 4 + r;
        if (w < NV) {
          int d = d0 + l15;
          atomicAdd(sum + (w << 8) + d, s1[mt][r]);
          atomicAdd(ssq + (w << 8) + d, s2[mt][r]);
        }
      }
  }
}

extern "C" void kernel_launch(void* const* d_in, const int* in_sizes, int n_in,
                              void* d_out, int out_size, void* d_ws, size_t ws_size,
                              hipStream_t stream) {
  const float* x0   = (const float*)d_in[0];
  const float* W    = (const float*)d_in[1];
  // d_in[2] = bias: cancels inside BN -> unused
  const float* mask = (const float*)d_in[3];
  const float* bnw  = (const float*)d_in[4];
  const float* bnb  = (const float*)d_in[5];
  // d_in[6], d_in[7] = shift tables: folded into addressing
  float* out = (float*)d_out;

  char* ws = (char*)d_ws;
  short* Wt     = (short*)ws;
  unsigned* tab = (unsigned*)(ws + 131072);
  float* sum    = (float*)(ws + 154624);
  float* ssq    = (float*)(ws + 178176);
  float* An2    = (float*)(ws + 201728);
  float* Bn2    = (float*)(ws + 225280);

  k_prep<<<256, 256, 0, stream>>>(W, mask, Wt, tab, sum);
  k_gemm<0><<<512, 1024, 32768, stream>>>(x0, Wt, tab, sum, ssq, nullptr, nullptr, nullptr);
  k_finalize<<<23, 256, 0, stream>>>(sum, ssq, bnw, bnb, An2, Bn2);
  k_gemm<1><<<512, 1024, 56320, stream>>>(x0, Wt, tab, sum, ssq, An2, Bn2, out);
}

// Round 7
// 318.068 us; speedup vs baseline: 1.4958x; 1.4951x over previous
//
#include <hip/hip_runtime.h>
#include <hip/hip_bf16.h>

#define NV 23
#define NTOT 16384
#define FLAT (NV * 256)    // 5888 floats per slab
#define FLAT4 (FLAT / 4)   // 1472
#define NB 32              // n per block
#define CH (FLAT4 / 16)    // 92 f32x4 per wave
#define NS 2               // reg slots per chunk
#define SLAB 23552         // slab bytes
#define ROFF 32768         // raw[3] @ 32768..103424
#define OOFF 103424        // O (pass 2 only)

typedef short s16x8 __attribute__((ext_vector_type(8)));
typedef float f32x4 __attribute__((ext_vector_type(4)));
typedef unsigned u32x4 __attribute__((ext_vector_type(4)));

// x/23 for 0 <= x < 61681
__device__ __forceinline__ int divNV(int x) { return (int)(((unsigned)x * 45591u) >> 20); }
// f32 -> bf16 bits, RNE
__device__ __forceinline__ unsigned f2bf(float f) {
  unsigned u = __float_as_uint(f);
  u += 0x7fffu + ((u >> 16) & 1u);
  return u >> 16;
}

// async global->LDS DMA, 16B per lane. LDS dest is wave-uniform base
// (HW adds lane*16); global src is per-lane. Pointer->int->addrspace-ptr
// casts: AS1 == flat VA for global; AS3 offset == low32 of flat LDS VA.
__device__ __forceinline__ void gl_lds16(const void* g, void* l) {
  __builtin_amdgcn_global_load_lds(
      (const __attribute__((address_space(1))) unsigned*)(unsigned long long)(uintptr_t)g,
      (__attribute__((address_space(3))) unsigned*)(unsigned)(uintptr_t)l, 16, 0, 0);
}

// ws layout (bytes): Wt@0 (131072) | tab@131072 (23552) | sum@154624 | ssq@178176
//                    | An2@201728 | Bn2@225280 -> 248832 total
__global__ void k_prep(const float* __restrict__ W, const float* __restrict__ mask,
                       short* __restrict__ Wt, unsigned* __restrict__ tab,
                       float* __restrict__ sums) {
  int idx = blockIdx.x * 256 + threadIdx.x;  // grid 256 -> 65536
  int d = idx >> 8, c = idx & 255;
  Wt[idx] = (short)f2bf(W[c * 256 + d]);     // W^T in bf16: Wt[d][c]
  if (idx < FLAT) {
    // p = idx = c*23 + v ; w = (v - c) mod 23 ; swizzled LDS byte offset
    int cc = divNV(idx);
    int v = idx - NV * cc;
    int cm = cc - NV * divNV(cc);
    int w = v - cm; w += (w >> 31) & NV;
    unsigned off = (unsigned)((w << 9) + ((cc << 1) ^ ((w & 7) << 4)));
    tab[idx] = (f2bf(tanhf(mask[(w << 8) + cc]) + 1.0f) << 16) | off;
  }
  if (idx < 2 * FLAT) sums[idx] = 0.0f;      // zero sum+ssq
}

__global__ void k_finalize(const float* __restrict__ sum, const float* __restrict__ ssq,
                           const float* __restrict__ bnw, const float* __restrict__ bnb,
                           float* __restrict__ An2, float* __restrict__ Bn2) {
  int idx = blockIdx.x * 256 + threadIdx.x;  // (w,d) feature in y-space
  if (idx >= FLAT) return;
  int w = idx >> 8, d = idx & 255;
  float mean = sum[idx] * (1.0f / NTOT);
  float var  = ssq[idx] * (1.0f / NTOT) - mean * mean;
  float inv  = rsqrtf(var + 1e-5f);
  int i = w + d; i -= NV * divNV(i);         // out-shift row i = (w+d) % 23
  float a = inv * bnw[i * 256 + d];
  An2[d * NV + i] = a;                       // j-indexed (flat out order)
  Bn2[d * NV + i] = bnb[i * 256 + d] - mean * a;
}

// WRITE=0: stats pass.  WRITE=1: recompute + normalize + residual + relu.
// 16 waves x 64. Wave wv owns d-strip [wv*16,wv*16+16) and slab chunk
// [wv*CH,(wv+1)*CH) f32x4. x0 slabs staged into LDS via async
// global_load_lds DMA (triple-buffered) -> ZERO load-destination VGPRs
// (R4-R6 post-mortem: spilled register prefetch forced vmcnt(0) per load,
// collapsing the pipeline; all reg-prefetch variants pinned at ~290us/pass).
// Phase t: vmcnt(own L(t+1) done) -> lgkm+barrier (ALL waves' L(t+1)
// visible) -> DMA L(t+2) -> form X'(t+1) -> MFMA(t) -> epilogue(t).
// raw roles per phase: read t (residual), read t+1 (form), write t+2 - all
// distinct mod 3; DMA-vs-reader races separated by the barrier.
template <int WRITE>
__global__ __launch_bounds__(1024) void k_gemm(
    const float* __restrict__ x0, const short* __restrict__ Wt,
    const unsigned* __restrict__ tab, float* __restrict__ sum, float* __restrict__ ssq,
    const float* __restrict__ An2, const float* __restrict__ Bn2,
    float* __restrict__ out) {
  __shared__ char smem[WRITE ? 126976 : 103424];  // X'[2] | raw[3] | (O)
  float* O = (float*)(smem + OOFF);

  const int tid = threadIdx.x;
  const int lane = tid & 63;
  const int wv = tid >> 6;
  const int l15 = lane & 15;
  const int lg = lane >> 4;
  const int d0 = wv * 16;
  const int ch0 = wv * CH;
  const bool act = (64 + lane) < CH;  // slot-1 active lanes (slot 0 always full)

  // B fragments, register-resident (32 VGPR): B[k=c][n=d] = Wt[d][c]
  s16x8 bfr[8];
#pragma unroll
  for (int kt = 0; kt < 8; ++kt)
    bfr[kt] = *(const s16x8*)(Wt + (d0 + l15) * 256 + kt * 32 + lg * 8);

  // formation table, register-resident (n-invariant)
  u32x4 tbr[NS];
  tbr[0] = *(const u32x4*)(tab + 4 * (ch0 + lane));
  if (act) tbr[1] = *(const u32x4*)(tab + 4 * (ch0 + 64 + lane));

  // BN affine tables, register-resident (n-invariant), WRITE only
  f32x4 anr[NS], bnr[NS];
  if (WRITE) {
    anr[0] = *(const f32x4*)(An2 + 4 * (ch0 + lane));
    bnr[0] = *(const f32x4*)(Bn2 + 4 * (ch0 + lane));
    if (act) {
      anr[1] = *(const f32x4*)(An2 + 4 * (ch0 + 64 + lane));
      bnr[1] = *(const f32x4*)(Bn2 + 4 * (ch0 + 64 + lane));
    }
  }

  // zero pad rows 23..31 of both X' buffers (never written again)
  for (int i = tid; i < 2304; i += 1024) {
    int b = i >= 1152;
    *(int*)(smem + b * 16384 + 11776 + (i - b * 1152) * 4) = 0;
  }

  float s1[2][4], s2[2][4];
  if (!WRITE) {
#pragma unroll
    for (int mt = 0; mt < 2; ++mt)
#pragma unroll
      for (int r = 0; r < 4; ++r) { s1[mt][r] = 0.f; s2[mt][r] = 0.f; }
  }

  const int nbase = blockIdx.x * NB;
  // pass 2 runs its window in reverse: pass 1 left the tail L3-resident
  auto nmap = [&](int T) { return nbase + (WRITE ? (NB - 1 - T) : T); };

  auto stage = [&](int T) {  // issue 2 async DMAs for slab T -> raw[T%3]
    if (T >= NB) return;
    const char* gs = (const char*)(x0 + (size_t)nmap(T) * FLAT);
    char* lb = smem + ROFF + (T % 3) * SLAB;
    int cA = wv;              // chunks 0..15
    int cB = 16 + (wv % 7);   // chunks 16..22 (duplicates idempotent)
    gl_lds16(gs + (cA << 10) + lane * 16, lb + (cA << 10));
    gl_lds16(gs + (cB << 10) + lane * 16, lb + (cB << 10));
  };
  auto form = [&](int T) {  // X' formation into Xb[T&1] from raw[T%3]
    if (T >= NB) return;
    const char* rb = smem + ROFF + (T % 3) * SLAB;
    char* xb = smem + (T & 1) * 16384;
#pragma unroll
    for (int s = 0; s < NS; ++s)
      if (s == 0 || act) {
        f32x4 xv = *(const f32x4*)(rb + (ch0 + s * 64 + lane) * 16);
        u32x4 tb = tbr[s];
#pragma unroll
        for (int e = 0; e < 4; ++e) {
          unsigned tt = tb[e];
          *(short*)(xb + (tt & 0xffffu)) =
              (short)f2bf(xv[e] * __uint_as_float(tt & 0xffff0000u));
        }
      }
  };
  auto bar = []() {  // LDS-drain barrier: does NOT drain vmcnt
    asm volatile("s_waitcnt lgkmcnt(0)" ::: "memory");
    __builtin_amdgcn_s_barrier();
    asm volatile("" ::: "memory");
  };

  // prologue: fill 2 slabs, drain, barrier, form slab 0
  stage(0);
  stage(1);
  asm volatile("s_waitcnt vmcnt(0)" ::: "memory");
  bar();
  form(0);

  for (int t = 0; t < NB; ++t) {
    // own L(t+1) complete (2 newest allowed outstanding = S(t-1) stores)
    if (WRITE && t) asm volatile("s_waitcnt vmcnt(2)" ::: "memory");
    else            asm volatile("s_waitcnt vmcnt(0)" ::: "memory");
    bar();  // ALL waves' L(t+1) visible; X'(t) forms visible; raw readers done
    stage(t + 2);
    form(t + 1);

    // ---- MFMA: y[w,d] = X'(t)[w,c] * W[c,d] ----
    const char* xb = smem + (t & 1) * 16384;
    f32x4 acc[2];
    acc[0] = (f32x4){0.f, 0.f, 0.f, 0.f};
    acc[1] = (f32x4){0.f, 0.f, 0.f, 0.f};
#pragma unroll
    for (int kt = 0; kt < 8; ++kt) {
      s16x8 af[2];
#pragma unroll
      for (int mt = 0; mt < 2; ++mt) {
        int row = mt * 16 + l15;
        af[mt] = *(const s16x8*)(xb + (row << 9) +
                                 (((kt * 32 + lg * 8) << 1) ^ ((row & 7) << 4)));
      }
#pragma unroll
      for (int mt = 0; mt < 2; ++mt)
        acc[mt] = __builtin_amdgcn_mfma_f32_16x16x32_bf16(af[mt], bfr[kt], acc[mt], 0, 0, 0);
    }

    if (!WRITE) {
#pragma unroll
      for (int mt = 0; mt < 2; ++mt)
#pragma unroll
        for (int r = 0; r < 4; ++r) {
          float y = acc[mt][r];
          s1[mt][r] += y;
          s2[mt][r] += y * y;
        }
    } else {
      // scatter y -> O at out-shifted j = d*23 + (w+d)%23 (wave-local region)
#pragma unroll
      for (int mt = 0; mt < 2; ++mt)
#pragma unroll
        for (int r = 0; r < 4; ++r) {
          int w = mt * 16 + lg * 4 + r;  // C/D: row = (lane>>4)*4 + reg
          if (w < NV) {
            int d = d0 + l15;            // col = lane & 15
            int sj = w + d; sj -= NV * divNV(sj);
            O[d * NV + sj] = acc[mt][r];
          }
        }
      // same-wave readback: normalize + residual (raw LDS) + relu, NT store
      const char* rb = smem + ROFF + (t % 3) * SLAB;
      float* og = out + (size_t)nmap(t) * FLAT;
#pragma unroll
      for (int s = 0; s < NS; ++s)
        if (s == 0 || act) {
          int i = ch0 + s * 64 + lane;
          f32x4 y = *(const f32x4*)(O + 4 * i);
          f32x4 sl = *(const f32x4*)(rb + i * 16);
          f32x4 o;
#pragma unroll
          for (int e = 0; e < 4; ++e)
            o[e] = fmaxf(fmaf(y[e], anr[s][e], bnr[s][e]) + sl[e], 0.0f);
          __builtin_nontemporal_store(o, (f32x4*)og + i);
        }
    }
  }

  if (!WRITE) {
#pragma unroll
    for (int mt = 0; mt < 2; ++mt)
#pragma unroll
      for (int r = 0; r < 4; ++r) {
        int w = mt * 16 + lg * 4 + r;
        if (w < NV) {
          int d = d0 + l15;
          atomicAdd(sum + (w << 8) + d, s1[mt][r]);
          atomicAdd(ssq + (w << 8) + d, s2[mt][r]);
        }
      }
  }
}

extern "C" void kernel_launch(void* const* d_in, const int* in_sizes, int n_in,
                              void* d_out, int out_size, void* d_ws, size_t ws_size,
                              hipStream_t stream) {
  const float* x0   = (const float*)d_in[0];
  const float* W    = (const float*)d_in[1];
  // d_in[2] = bias: cancels inside BN -> unused
  const float* mask = (const float*)d_in[3];
  const float* bnw  = (const float*)d_in[4];
  const float* bnb  = (const float*)d_in[5];
  // d_in[6], d_in[7] = shift tables: folded into addressing
  float* out = (float*)d_out;

  char* ws = (char*)d_ws;
  short* Wt     = (short*)ws;
  unsigned* tab = (unsigned*)(ws + 131072);
  float* sum    = (float*)(ws + 154624);
  float* ssq    = (float*)(ws + 178176);
  float* An2    = (float*)(ws + 201728);
  float* Bn2    = (float*)(ws + 225280);

  k_prep<<<256, 256, 0, stream>>>(W, mask, Wt, tab, sum);
  k_gemm<0><<<512, 1024, 0, stream>>>(x0, Wt, tab, sum, ssq, nullptr, nullptr, nullptr);
  k_finalize<<<23, 256, 0, stream>>>(sum, ssq, bnw, bnb, An2, Bn2);
  k_gemm<1><<<512, 1024, 0, stream>>>(x0, Wt, tab, sum, ssq, An2, Bn2, out);
}

// Round 8
// 280.083 us; speedup vs baseline: 1.6986x; 1.1356x over previous
//
#include <hip/hip_runtime.h>
#include <hip/hip_bf16.h>

#define NV 23
#define NTOT 16384
#define FLAT (NV * 256)    // 5888 floats per slab
#define FLAT4 (FLAT / 4)   // 1472
#define NB 32              // n per block
#define CH 184             // f32x4 per wave (1472/8)
#define NS 3               // reg slots per chunk (64+64+56)
#define SLAB 23552         // slab bytes
#define ROFF 32768         // raw[3] @ 32768..103424
#define OOFF 103424        // O (pass 2 only)

typedef short s16x8 __attribute__((ext_vector_type(8)));
typedef float f32x4 __attribute__((ext_vector_type(4)));
typedef unsigned u32x4 __attribute__((ext_vector_type(4)));

// x/23 for 0 <= x < 61681
__device__ __forceinline__ int divNV(int x) { return (int)(((unsigned)x * 45591u) >> 20); }
// f32 -> bf16 bits, RNE
__device__ __forceinline__ unsigned f2bf(float f) {
  unsigned u = __float_as_uint(f);
  u += 0x7fffu + ((u >> 16) & 1u);
  return u >> 16;
}

// async global->LDS DMA, 16B per lane (lds dest wave-uniform, HW adds lane*16)
__device__ __forceinline__ void gl_lds16(const void* g, void* l) {
  __builtin_amdgcn_global_load_lds(
      (const __attribute__((address_space(1))) unsigned*)(unsigned long long)(uintptr_t)g,
      (__attribute__((address_space(3))) unsigned*)(unsigned)(uintptr_t)l, 16, 0, 0);
}

// ws layout (bytes): Wt@0 (131072) | tab@131072 (23552) | sum@154624 | ssq@178176
//                    | An2@201728 | Bn2@225280 -> 248832 total
__global__ void k_prep(const float* __restrict__ W, const float* __restrict__ mask,
                       short* __restrict__ Wt, unsigned* __restrict__ tab,
                       float* __restrict__ sums) {
  int idx = blockIdx.x * 256 + threadIdx.x;  // grid 256 -> 65536
  int d = idx >> 8, c = idx & 255;
  Wt[idx] = (short)f2bf(W[c * 256 + d]);     // W^T in bf16: Wt[d][c]
  if (idx < FLAT) {
    // p = idx = c*23 + v ; w = (v - c) mod 23 ; swizzled LDS byte offset
    int cc = divNV(idx);
    int v = idx - NV * cc;
    int cm = cc - NV * divNV(cc);
    int w = v - cm; w += (w >> 31) & NV;
    unsigned off = (unsigned)((w << 9) + ((cc << 1) ^ ((w & 7) << 4)));
    tab[idx] = (f2bf(tanhf(mask[(w << 8) + cc]) + 1.0f) << 16) | off;
  }
  if (idx < 2 * FLAT) sums[idx] = 0.0f;      // zero sum+ssq
}

__global__ void k_finalize(const float* __restrict__ sum, const float* __restrict__ ssq,
                           const float* __restrict__ bnw, const float* __restrict__ bnb,
                           float* __restrict__ An2, float* __restrict__ Bn2) {
  int idx = blockIdx.x * 256 + threadIdx.x;  // (w,d) feature in y-space
  if (idx >= FLAT) return;
  int w = idx >> 8, d = idx & 255;
  float mean = sum[idx] * (1.0f / NTOT);
  float var  = ssq[idx] * (1.0f / NTOT) - mean * mean;
  float inv  = rsqrtf(var + 1e-5f);
  int i = w + d; i -= NV * divNV(i);         // out-shift row i = (w+d) % 23
  float a = inv * bnw[i * 256 + d];
  An2[d * NV + i] = a;                       // j-indexed (flat out order)
  Bn2[d * NV + i] = bnb[i * 256 + d] - mean * a;
}

// WRITE=0: stats pass.  WRITE=1: recompute + normalize + residual + relu.
// 8 waves x 64 (R7 post-mortem: phase was LDS-BW-bound on A-fragment
// re-reads = WAVES x 16KB/slab; 16->8 waves halves it). Wave wv owns
// d-strip [wv*32,wv*32+32) (NT=2) and slab chunk [wv*CH,(wv+1)*CH) f32x4.
// x0 slabs staged to LDS via async global_load_lds (triple-buffered,
// 23 DMAs exact). 512 thr + >100KB LDS -> 1 block/CU -> 2 waves/SIMD ->
// 256-VGPR budget (allocator can't 64-cap us).
// Phase t: vmcnt(own L(t+1) done) -> lgkm+barrier -> DMA L(t+2) ->
// form X'(t+1) -> MFMA(t) -> epilogue(t). raw roles t/t+1/t+2 mod 3.
template <int WRITE>
__global__ __launch_bounds__(512) void k_gemm(
    const float* __restrict__ x0, const short* __restrict__ Wt,
    const unsigned* __restrict__ tab, float* __restrict__ sum, float* __restrict__ ssq,
    const float* __restrict__ An2, const float* __restrict__ Bn2,
    float* __restrict__ out) {
  __shared__ char smem[WRITE ? 126976 : 103424];  // X'[2] | raw[3] | (O)
  float* O = (float*)(smem + OOFF);

  const int tid = threadIdx.x;
  const int lane = tid & 63;
  const int wv = tid >> 6;     // 0..7
  const int l15 = lane & 15;
  const int lg = lane >> 4;
  const int d0 = wv * 32;
  const int ch0 = wv * CH;

  // B fragments, register-resident (64 VGPR): B[k=c][n=d] = Wt[d][c]
  s16x8 bfr[2][8];
#pragma unroll
  for (int nt = 0; nt < 2; ++nt)
#pragma unroll
    for (int kt = 0; kt < 8; ++kt)
      bfr[nt][kt] = *(const s16x8*)(Wt + (d0 + nt * 16 + l15) * 256 + kt * 32 + lg * 8);

  // formation table, register-resident (n-invariant)
  u32x4 tbr[NS];
#pragma unroll
  for (int s = 0; s < NS; ++s)
    if (s * 64 + lane < CH) tbr[s] = *(const u32x4*)(tab + 4 * (ch0 + s * 64 + lane));

  // BN affine tables, register-resident (n-invariant), WRITE only
  f32x4 anr[NS], bnr[NS];
  if (WRITE) {
#pragma unroll
    for (int s = 0; s < NS; ++s)
      if (s * 64 + lane < CH) {
        anr[s] = *(const f32x4*)(An2 + 4 * (ch0 + s * 64 + lane));
        bnr[s] = *(const f32x4*)(Bn2 + 4 * (ch0 + s * 64 + lane));
      }
  }

  // zero pad rows 23..31 of both X' buffers (never written again)
  for (int i = tid; i < 2304; i += 512) {
    int b = i >= 1152;
    *(int*)(smem + b * 16384 + 11776 + (i - b * 1152) * 4) = 0;
  }

  float s1[2][2][4], s2[2][2][4];
  if (!WRITE) {
#pragma unroll
    for (int mt = 0; mt < 2; ++mt)
#pragma unroll
      for (int nt = 0; nt < 2; ++nt)
#pragma unroll
        for (int r = 0; r < 4; ++r) { s1[mt][nt][r] = 0.f; s2[mt][nt][r] = 0.f; }
  }

  const int nbase = blockIdx.x * NB;
  // pass 2 runs its window in reverse: pass 1 left the tail L3-resident
  auto nmap = [&](int T) { return nbase + (WRITE ? (NB - 1 - T) : T); };

  auto stage = [&](int T) {  // 23 exact DMAs for slab T -> raw[T%3]
    if (T >= NB) return;
    const char* gs = (const char*)(x0 + (size_t)nmap(T) * FLAT);
    char* lb = smem + ROFF + (T % 3) * SLAB;
    gl_lds16(gs + (wv << 10) + lane * 16, lb + (wv << 10));
    gl_lds16(gs + ((8 + wv) << 10) + lane * 16, lb + ((8 + wv) << 10));
    if (wv < 7)
      gl_lds16(gs + ((16 + wv) << 10) + lane * 16, lb + ((16 + wv) << 10));
  };
  auto form = [&](int T) {  // X' formation into Xb[T&1] from raw[T%3]
    if (T >= NB) return;
    const char* rb = smem + ROFF + (T % 3) * SLAB;
    char* xb = smem + (T & 1) * 16384;
#pragma unroll
    for (int s = 0; s < NS; ++s)
      if (s * 64 + lane < CH) {
        f32x4 xv = *(const f32x4*)(rb + (ch0 + s * 64 + lane) * 16);
        u32x4 tb = tbr[s];
#pragma unroll
        for (int e = 0; e < 4; ++e) {
          unsigned tt = tb[e];
          *(short*)(xb + (tt & 0xffffu)) =
              (short)f2bf(xv[e] * __uint_as_float(tt & 0xffff0000u));
        }
      }
  };
  auto bar = []() {  // LDS-drain barrier: does NOT drain vmcnt
    asm volatile("s_waitcnt lgkmcnt(0)" ::: "memory");
    __builtin_amdgcn_s_barrier();
    asm volatile("" ::: "memory");
  };

  // prologue: fill 2 slabs, drain, barrier, form slab 0
  stage(0);
  stage(1);
  asm volatile("s_waitcnt vmcnt(0)" ::: "memory");
  bar();
  form(0);

  for (int t = 0; t < NB; ++t) {
    // own L(t+1) DMAs complete; pass2: allow epilogue(t-1) NT stores (3) to linger
    if (WRITE && t) asm volatile("s_waitcnt vmcnt(3)" ::: "memory");
    else            asm volatile("s_waitcnt vmcnt(0)" ::: "memory");
    bar();  // ALL waves' L(t+1) visible; X'(t) form visible; raw readers done
    stage(t + 2);
    form(t + 1);

    // ---- MFMA: y[w,d] = X'(t)[w,c] * W[c,d] ----
    const char* xb = smem + (t & 1) * 16384;
    f32x4 acc[2][2];
#pragma unroll
    for (int mt = 0; mt < 2; ++mt)
#pragma unroll
      for (int nt = 0; nt < 2; ++nt) acc[mt][nt] = (f32x4){0.f, 0.f, 0.f, 0.f};
#pragma unroll
    for (int kt = 0; kt < 8; ++kt) {
      s16x8 af[2];
#pragma unroll
      for (int mt = 0; mt < 2; ++mt) {
        int row = mt * 16 + l15;
        af[mt] = *(const s16x8*)(xb + (row << 9) +
                                 (((kt * 32 + lg * 8) << 1) ^ ((row & 7) << 4)));
      }
#pragma unroll
      for (int mt = 0; mt < 2; ++mt)
#pragma unroll
        for (int nt = 0; nt < 2; ++nt)
          acc[mt][nt] = __builtin_amdgcn_mfma_f32_16x16x32_bf16(
              af[mt], bfr[nt][kt], acc[mt][nt], 0, 0, 0);
    }

    if (!WRITE) {
#pragma unroll
      for (int mt = 0; mt < 2; ++mt)
#pragma unroll
        for (int nt = 0; nt < 2; ++nt)
#pragma unroll
          for (int r = 0; r < 4; ++r) {
            float y = acc[mt][nt][r];
            s1[mt][nt][r] += y;
            s2[mt][nt][r] += y * y;
          }
    } else {
      // scatter y -> O at out-shifted j = d*23 + (w+d)%23 (wave-local region)
#pragma unroll
      for (int mt = 0; mt < 2; ++mt)
#pragma unroll
        for (int nt = 0; nt < 2; ++nt)
#pragma unroll
          for (int r = 0; r < 4; ++r) {
            int w = mt * 16 + lg * 4 + r;  // C/D: row = (lane>>4)*4 + reg
            if (w < NV) {
              int d = d0 + nt * 16 + l15;  // col = lane & 15
              int sj = w + d; sj -= NV * divNV(sj);
              O[d * NV + sj] = acc[mt][nt][r];
            }
          }
      // same-wave readback: normalize + residual (raw LDS) + relu, NT store
      const char* rb = smem + ROFF + (t % 3) * SLAB;
      float* og = out + (size_t)nmap(t) * FLAT;
#pragma unroll
      for (int s = 0; s < NS; ++s)
        if (s * 64 + lane < CH) {
          int i = ch0 + s * 64 + lane;
          f32x4 y = *(const f32x4*)(O + 4 * i);
          f32x4 sl = *(const f32x4*)(rb + i * 16);
          f32x4 o;
#pragma unroll
          for (int e = 0; e < 4; ++e)
            o[e] = fmaxf(fmaf(y[e], anr[s][e], bnr[s][e]) + sl[e], 0.0f);
          __builtin_nontemporal_store(o, (f32x4*)og + i);
        }
    }
  }

  if (!WRITE) {
#pragma unroll
    for (int mt = 0; mt < 2; ++mt)
#pragma unroll
      for (int nt = 0; nt < 2; ++nt)
#pragma unroll
        for (int r = 0; r < 4; ++r) {
          int w = mt * 16 + lg * 4 + r;
          if (w < NV) {
            int d = d0 + nt * 16 + l15;
            atomicAdd(sum + (w << 8) + d, s1[mt][nt][r]);
            atomicAdd(ssq + (w << 8) + d, s2[mt][nt][r]);
          }
        }
  }
}

extern "C" void kernel_launch(void* const* d_in, const int* in_sizes, int n_in,
                              void* d_out, int out_size, void* d_ws, size_t ws_size,
                              hipStream_t stream) {
  const float* x0   = (const float*)d_in[0];
  const float* W    = (const float*)d_in[1];
  // d_in[2] = bias: cancels inside BN -> unused
  const float* mask = (const float*)d_in[3];
  const float* bnw  = (const float*)d_in[4];
  const float* bnb  = (const float*)d_in[5];
  // d_in[6], d_in[7] = shift tables: folded into addressing
  float* out = (float*)d_out;

  char* ws = (char*)d_ws;
  short* Wt     = (short*)ws;
  unsigned* tab = (unsigned*)(ws + 131072);
  float* sum    = (float*)(ws + 154624);
  float* ssq    = (float*)(ws + 178176);
  float* An2    = (float*)(ws + 201728);
  float* Bn2    = (float*)(ws + 225280);

  k_prep<<<256, 256, 0, stream>>>(W, mask, Wt, tab, sum);
  k_gemm<0><<<512, 512, 0, stream>>>(x0, Wt, tab, sum, ssq, nullptr, nullptr, nullptr);
  k_finalize<<<23, 256, 0, stream>>>(sum, ssq, bnw, bnb, An2, Bn2);
  k_gemm<1><<<512, 512, 0, stream>>>(x0, Wt, tab, sum, ssq, An2, Bn2, out);
}

// Round 9
// 277.806 us; speedup vs baseline: 1.7126x; 1.0082x over previous
//
#include <hip/hip_runtime.h>
#include <hip/hip_bf16.h>

#define NV 23
#define NTOT 16384
#define FLAT (NV * 256)    // 5888 floats per slab
#define FLAT4 (FLAT / 4)   // 1472
#define CH 184             // f32x4 per wave (1472/8)
#define NS 3               // reg slots per chunk (64+64+56)
#define SLAB 23552         // slab bytes

// stats pass: X'[4] @0 (65536) | raw[4] @65536 (94208) -> 159744, grid 256 x NB0=64
#define NB0 64
#define ROFF0 65536
// write pass: X'[2] @0 (32768) | raw[3] @32768 (70656) | O @103424 -> 126976, grid 512 x NB1=32
#define NB1 32
#define ROFF1 32768
#define OOFF1 103424

typedef short s16x8 __attribute__((ext_vector_type(8)));
typedef float f32x4 __attribute__((ext_vector_type(4)));
typedef unsigned u32x4 __attribute__((ext_vector_type(4)));

// x/23 for 0 <= x < 61681
__device__ __forceinline__ int divNV(int x) { return (int)(((unsigned)x * 45591u) >> 20); }
// f32 -> bf16 bits, RNE
__device__ __forceinline__ unsigned f2bf(float f) {
  unsigned u = __float_as_uint(f);
  u += 0x7fffu + ((u >> 16) & 1u);
  return u >> 16;
}
// X' column swizzle (16-B granules). R8's (w&7) degenerated: same-c form lanes
// step w by 4 so w&7 took 2 values -> 3-way write conflicts (2.2e7 cycles).
// ((w + w/8)*3)&7 gives 6 distinct groups for w strides of 4, and read-side
// rows r,r' sharing f(r) are exactly pairs -> 2-way (free).
__device__ __forceinline__ int fsw(int w) { return ((w + (w >> 3)) * 3) & 7; }

// async global->LDS DMA, 16B per lane (lds dest wave-uniform, HW adds lane*16)
__device__ __forceinline__ void gl_lds16(const void* g, void* l) {
  __builtin_amdgcn_global_load_lds(
      (const __attribute__((address_space(1))) unsigned*)(unsigned long long)(uintptr_t)g,
      (__attribute__((address_space(3))) unsigned*)(unsigned)(uintptr_t)l, 16, 0, 0);
}

// ws layout (bytes): Wt@0 (131072) | tab@131072 (23552) | sum@154624 | ssq@178176
//                    | An2@201728 | Bn2@225280 -> 248832 total
__global__ void k_prep(const float* __restrict__ W, const float* __restrict__ mask,
                       short* __restrict__ Wt, unsigned* __restrict__ tab,
                       float* __restrict__ sums) {
  int idx = blockIdx.x * 256 + threadIdx.x;  // grid 256 -> 65536
  int d = idx >> 8, c = idx & 255;
  Wt[idx] = (short)f2bf(W[c * 256 + d]);     // W^T in bf16: Wt[d][c]
  if (idx < FLAT) {
    // p = idx = c*23 + v ; w = (v - c) mod 23 ; swizzled LDS byte offset
    int cc = divNV(idx);
    int v = idx - NV * cc;
    int cm = cc - NV * divNV(cc);
    int w = v - cm; w += (w >> 31) & NV;
    unsigned off = (unsigned)((w << 9) + ((cc << 1) ^ (fsw(w) << 4)));
    tab[idx] = (f2bf(tanhf(mask[(w << 8) + cc]) + 1.0f) << 16) | off;
  }
  if (idx < 2 * FLAT) sums[idx] = 0.0f;      // zero sum+ssq
}

__global__ void k_finalize(const float* __restrict__ sum, const float* __restrict__ ssq,
                           const float* __restrict__ bnw, const float* __restrict__ bnb,
                           float* __restrict__ An2, float* __restrict__ Bn2) {
  int idx = blockIdx.x * 256 + threadIdx.x;  // (w,d) feature in y-space
  if (idx >= FLAT) return;
  int w = idx >> 8, d = idx & 255;
  float mean = sum[idx] * (1.0f / NTOT);
  float var  = ssq[idx] * (1.0f / NTOT) - mean * mean;
  float inv  = rsqrtf(var + 1e-5f);
  int i = w + d; i -= NV * divNV(i);         // out-shift row i = (w+d) % 23
  float a = inv * bnw[i * 256 + d];
  An2[d * NV + i] = a;                       // j-indexed (flat out order)
  Bn2[d * NV + i] = bnb[i * 256 + d] - mean * a;
}

// WRITE=0: stats pass, 2 slabs/phase (halved barrier count), X'[4]+raw[4].
// WRITE=1: output pass, 1 slab/phase, X'[2]+raw[3]+O (R8 structure).
// 8 waves x 64. Wave wv owns d-strip [wv*32,wv*32+32) and slab chunk
// [wv*CH,(wv+1)*CH) f32x4. x0 staged to LDS via async global_load_lds.
template <int WRITE>
__global__ __launch_bounds__(512) void k_gemm(
    const float* __restrict__ x0, const short* __restrict__ Wt,
    const unsigned* __restrict__ tab, float* __restrict__ sum, float* __restrict__ ssq,
    const float* __restrict__ An2, const float* __restrict__ Bn2,
    float* __restrict__ out) {
  __shared__ char smem[WRITE ? 126976 : 159744];
  constexpr int ROFF = WRITE ? ROFF1 : ROFF0;
  constexpr int NXB = WRITE ? 2 : 4;   // X' buffers
  constexpr int NRB = WRITE ? 3 : 4;   // raw buffers
  constexpr int NB  = WRITE ? NB1 : NB0;
  float* O = (float*)(smem + OOFF1);

  const int tid = threadIdx.x;
  const int lane = tid & 63;
  const int wv = tid >> 6;     // 0..7
  const int l15 = lane & 15;
  const int lg = lane >> 4;
  const int d0 = wv * 32;
  const int ch0 = wv * CH;
  const int fr0 = fsw(l15) << 4;        // read-side swizzle, rows l15 / 16+l15
  const int fr1 = fsw(16 + l15) << 4;

  // B fragments, register-resident (64 VGPR): B[k=c][n=d] = Wt[d][c]
  s16x8 bfr[2][8];
#pragma unroll
  for (int nt = 0; nt < 2; ++nt)
#pragma unroll
    for (int kt = 0; kt < 8; ++kt)
      bfr[nt][kt] = *(const s16x8*)(Wt + (d0 + nt * 16 + l15) * 256 + kt * 32 + lg * 8);

  // formation table, register-resident (n-invariant)
  u32x4 tbr[NS];
#pragma unroll
  for (int s = 0; s < NS; ++s)
    if (s * 64 + lane < CH) tbr[s] = *(const u32x4*)(tab + 4 * (ch0 + s * 64 + lane));

  // BN affine tables, register-resident (n-invariant), WRITE only
  f32x4 anr[NS], bnr[NS];
  if (WRITE) {
#pragma unroll
    for (int s = 0; s < NS; ++s)
      if (s * 64 + lane < CH) {
        anr[s] = *(const f32x4*)(An2 + 4 * (ch0 + s * 64 + lane));
        bnr[s] = *(const f32x4*)(Bn2 + 4 * (ch0 + s * 64 + lane));
      }
  }

  // zero pad rows 23..31 of all X' buffers (never written again)
  for (int i = tid; i < NXB * 1152; i += 512) {
    int b = i / 1152;
    *(int*)(smem + b * 16384 + 11776 + (i - b * 1152) * 4) = 0;
  }

  float s1[2][2][4], s2[2][2][4];
  if (!WRITE) {
#pragma unroll
    for (int mt = 0; mt < 2; ++mt)
#pragma unroll
      for (int nt = 0; nt < 2; ++nt)
#pragma unroll
        for (int r = 0; r < 4; ++r) { s1[mt][nt][r] = 0.f; s2[mt][nt][r] = 0.f; }
  }

  const int nbase = blockIdx.x * NB;
  // pass 2 runs its window in reverse: pass 1 left the tail L3-resident
  auto nmap = [&](int T) { return nbase + (WRITE ? (NB - 1 - T) : T); };

  auto stage = [&](int T) {  // 23 exact DMAs for slab T -> raw[T%NRB]
    if (T >= NB) return;
    const char* gs = (const char*)(x0 + (size_t)nmap(T) * FLAT);
    char* lb = smem + ROFF + (T % NRB) * SLAB;
    gl_lds16(gs + (wv << 10) + lane * 16, lb + (wv << 10));
    gl_lds16(gs + ((8 + wv) << 10) + lane * 16, lb + ((8 + wv) << 10));
    if (wv < 7)
      gl_lds16(gs + ((16 + wv) << 10) + lane * 16, lb + ((16 + wv) << 10));
  };
  auto form = [&](int T) {  // X' formation into Xb[T%NXB] from raw[T%NRB]
    if (T >= NB) return;
    const char* rb = smem + ROFF + (T % NRB) * SLAB;
    char* xb = smem + (T % NXB) * 16384;
#pragma unroll
    for (int s = 0; s < NS; ++s)
      if (s * 64 + lane < CH) {
        f32x4 xv = *(const f32x4*)(rb + (ch0 + s * 64 + lane) * 16);
        u32x4 tb = tbr[s];
#pragma unroll
        for (int e = 0; e < 4; ++e) {
          unsigned tt = tb[e];
          *(short*)(xb + (tt & 0xffffu)) =
              (short)f2bf(xv[e] * __uint_as_float(tt & 0xffff0000u));
        }
      }
  };
  auto mstep = [&](int T, f32x4 (*acc)[2]) {  // y = X'(T) * W
    const char* xb = smem + (T % NXB) * 16384;
#pragma unroll
    for (int kt = 0; kt < 8; ++kt) {
      s16x8 af[2];
      af[0] = *(const s16x8*)(xb + (l15 << 9) + ((kt * 64 + lg * 16) ^ fr0));
      af[1] = *(const s16x8*)(xb + ((16 + l15) << 9) + ((kt * 64 + lg * 16) ^ fr1));
#pragma unroll
      for (int mt = 0; mt < 2; ++mt)
#pragma unroll
        for (int nt = 0; nt < 2; ++nt)
          acc[mt][nt] = __builtin_amdgcn_mfma_f32_16x16x32_bf16(
              af[mt], bfr[nt][kt], acc[mt][nt], 0, 0, 0);
    }
  };
  auto sstep = [&](f32x4 (*acc)[2]) {
#pragma unroll
    for (int mt = 0; mt < 2; ++mt)
#pragma unroll
      for (int nt = 0; nt < 2; ++nt)
#pragma unroll
        for (int r = 0; r < 4; ++r) {
          float y = acc[mt][nt][r];
          s1[mt][nt][r] += y;
          s2[mt][nt][r] += y * y;
        }
  };
  auto bar = []() {  // LDS-drain barrier: does NOT drain vmcnt
    asm volatile("s_waitcnt lgkmcnt(0)" ::: "memory");
    __builtin_amdgcn_s_barrier();
    asm volatile("" ::: "memory");
  };

  if (!WRITE) {
    // ---------------- stats pass: 2 slabs per phase ----------------
    stage(0); stage(1); stage(2); stage(3);
    asm volatile("s_waitcnt vmcnt(0)" ::: "memory");
    bar();
    form(0); form(1);
    for (int u = 0; u < NB0 / 2; ++u) {
      int t = 2 * u;
      asm volatile("s_waitcnt vmcnt(0)" ::: "memory");  // own DMAs pair u+1 done
      bar();  // all waves' DMAs + forms visible; X' readers of prev phase done
      stage(t + 4); stage(t + 5);
      form(t + 2); form(t + 3);
      f32x4 acc[2][2];
      __builtin_amdgcn_s_setprio(1);
#pragma unroll
      for (int mt = 0; mt < 2; ++mt)
#pragma unroll
        for (int nt = 0; nt < 2; ++nt) acc[mt][nt] = (f32x4){0.f, 0.f, 0.f, 0.f};
      mstep(t, acc);
      sstep(acc);
#pragma unroll
      for (int mt = 0; mt < 2; ++mt)
#pragma unroll
        for (int nt = 0; nt < 2; ++nt) acc[mt][nt] = (f32x4){0.f, 0.f, 0.f, 0.f};
      mstep(t + 1, acc);
      __builtin_amdgcn_s_setprio(0);
      sstep(acc);
    }
#pragma unroll
    for (int mt = 0; mt < 2; ++mt)
#pragma unroll
      for (int nt = 0; nt < 2; ++nt)
#pragma unroll
        for (int r = 0; r < 4; ++r) {
          int w = mt * 16 + lg * 4 + r;
          if (w < NV) {
            int d = d0 + nt * 16 + l15;
            atomicAdd(sum + (w << 8) + d, s1[mt][nt][r]);
            atomicAdd(ssq + (w << 8) + d, s2[mt][nt][r]);
          }
        }
    return;
  }

  // ---------------- output pass: 1 slab per phase (R8) ----------------
  stage(0); stage(1);
  asm volatile("s_waitcnt vmcnt(0)" ::: "memory");
  bar();
  form(0);

  for (int t = 0; t < NB1; ++t) {
    // own L(t+1) DMAs complete; allow epilogue(t-1) NT stores (3) to linger
    if (t) asm volatile("s_waitcnt vmcnt(3)" ::: "memory");
    else   asm volatile("s_waitcnt vmcnt(0)" ::: "memory");
    bar();  // all waves' L(t+1) + X'(t) form visible; raw/X' readers done
    stage(t + 2);
    form(t + 1);

    f32x4 acc[2][2];
#pragma unroll
    for (int mt = 0; mt < 2; ++mt)
#pragma unroll
      for (int nt = 0; nt < 2; ++nt) acc[mt][nt] = (f32x4){0.f, 0.f, 0.f, 0.f};
    __builtin_amdgcn_s_setprio(1);
    mstep(t, acc);
    __builtin_amdgcn_s_setprio(0);

    // scatter y -> O at out-shifted j = d*23 + (w+d)%23 (wave-local region)
#pragma unroll
    for (int mt = 0; mt < 2; ++mt)
#pragma unroll
      for (int nt = 0; nt < 2; ++nt)
#pragma unroll
        for (int r = 0; r < 4; ++r) {
          int w = mt * 16 + lg * 4 + r;  // C/D: row = (lane>>4)*4 + reg
          if (w < NV) {
            int d = d0 + nt * 16 + l15;  // col = lane & 15
            int sj = w + d; sj -= NV * divNV(sj);
            O[d * NV + sj] = acc[mt][nt][r];
          }
        }
    // same-wave readback: normalize + residual (raw LDS) + relu, NT store
    const char* rb = smem + ROFF + (t % NRB) * SLAB;
    float* og = out + (size_t)nmap(t) * FLAT;
#pragma unroll
    for (int s = 0; s < NS; ++s)
      if (s * 64 + lane < CH) {
        int i = ch0 + s * 64 + lane;
        f32x4 y = *(const f32x4*)(O + 4 * i);
        f32x4 sl = *(const f32x4*)(rb + i * 16);
        f32x4 o;
#pragma unroll
        for (int e = 0; e < 4; ++e)
          o[e] = fmaxf(fmaf(y[e], anr[s][e], bnr[s][e]) + sl[e], 0.0f);
        __builtin_nontemporal_store(o, (f32x4*)og + i);
      }
  }
}

extern "C" void kernel_launch(void* const* d_in, const int* in_sizes, int n_in,
                              void* d_out, int out_size, void* d_ws, size_t ws_size,
                              hipStream_t stream) {
  const float* x0   = (const float*)d_in[0];
  const float* W    = (const float*)d_in[1];
  // d_in[2] = bias: cancels inside BN -> unused
  const float* mask = (const float*)d_in[3];
  const float* bnw  = (const float*)d_in[4];
  const float* bnb  = (const float*)d_in[5];
  // d_in[6], d_in[7] = shift tables: folded into addressing
  float* out = (float*)d_out;

  char* ws = (char*)d_ws;
  short* Wt     = (short*)ws;
  unsigned* tab = (unsigned*)(ws + 131072);
  float* sum    = (float*)(ws + 154624);
  float* ssq    = (float*)(ws + 178176);
  float* An2    = (float*)(ws + 201728);
  float* Bn2    = (float*)(ws + 225280);

  k_prep<<<256, 256, 0, stream>>>(W, mask, Wt, tab, sum);
  k_gemm<0><<<256, 512, 0, stream>>>(x0, Wt, tab, sum, ssq, nullptr, nullptr, nullptr);
  k_finalize<<<23, 256, 0, stream>>>(sum, ssq, bnw, bnb, An2, Bn2);
  k_gemm<1><<<512, 512, 0, stream>>>(x0, Wt, tab, sum, ssq, An2, Bn2, out);
}